// Round 18
// baseline (168.941 us; speedup 1.0000x reference)
//
#include <hip/hip_runtime.h>
#include <stdint.h>

#define EPSN 1e-9f

typedef __fp16 f16x8 __attribute__((ext_vector_type(8)));
typedef float f32x4 __attribute__((ext_vector_type(4)));

// Wave-level LDS fence (rule #18: sched_barrier after waitcnt).
#define LDS_FENCE()                                        \
  do {                                                     \
    asm volatile("s_waitcnt lgkmcnt(0)" ::: "memory");     \
    __builtin_amdgcn_sched_barrier(0);                     \
  } while (0)

// ---------------------------------------------------------------------------
// ws layout (bytes):
//   [0)         inv1_1/inv2_1 f32 (fallback path)        98304
//   [98304)     w1h  [4][48][64][256] f16                6291456
//   [6389760)   w2h  same                                6291456
//   [12681216)  x1h0 [4][48][64][256] f16 (L0 strided    6291456
//               x1 pixels, NORMALIZED)
//   [18972672)  x2h0 [4][192][276][256] f16 (all x2_0    108527616
//               pixels NORMALIZED; pixels 0-3 & 260-275 zero pads)
//   full fast path needs 127500288 B.
// ---------------------------------------------------------------------------

__global__ __launch_bounds__(256) void norms1_kernel(
    const float* __restrict__ x1_1, const float* __restrict__ x2_1,
    float* __restrict__ ws) {
  int p = blockIdx.x * 256 + threadIdx.x;     // 24576 total
  const float* src = (p < 12288) ? x1_1 : x2_1;
  int q = (p < 12288) ? p : p - 12288;        // 12288 is NOT pow2
  long base = (long)(q / 3072) * 786432 + (q % 3072);
  float ss = 0.f;
#pragma unroll 8
  for (int c = 0; c < 256; ++c) { float v = src[base + (long)c * 3072]; ss += v * v; }
  ws[p] = 1.f / (sqrtf(ss) + EPSN);
}

// ---------------------------------------------------------------------------
// Level-0 x1 prep (r17-proven): normalize + f16 + transpose strided pixels:
// x1h0[b][i][j][c] = x1[b][c][4i][4j] / (||x1[b,:,4i,4j]||+eps). 192 blocks.
// ---------------------------------------------------------------------------
__global__ __launch_bounds__(256) void xpose0_kernel(
    const float* __restrict__ x1, __fp16* __restrict__ x1h0) {
  int bx = blockIdx.x;                        // 192 = 4 * 48
  int i = bx % 48, b = bx / 48;
  __fp16* dst = x1h0 + (long)(b * 48 + i) * 16384;  // 64*256
  __shared__ uint32_t lds[64 * 128];          // 64 rows x 512 B
  __shared__ float sred[4][64];
  int t = threadIdx.x;
  int j = t & 63, cg = t >> 6;                // wave = cg
  const float* sp = x1 + (long)b * 12582912 + (long)(4 * i) * 256 + 4 * j;
  float vv[64];
  float ss = 0.f;
#pragma unroll
  for (int c8 = 0; c8 < 64; ++c8) {
    float v = sp[(long)(cg * 64 + c8) * 49152];
    vv[c8] = v;
    ss += v * v;
  }
  sred[cg][j] = ss;
  __syncthreads();
  float invv = 1.f / (sqrtf(sred[0][j] + sred[1][j] + sred[2][j] + sred[3][j]) + EPSN);
#pragma unroll
  for (int cb = 0; cb < 8; ++cb) {
    uint32_t pk[4];
#pragma unroll
    for (int e2 = 0; e2 < 4; ++e2) {
      int cl = cb * 8 + e2 * 2;
      __fp16 h0 = (__fp16)(vv[cl] * invv);
      __fp16 h1 = (__fp16)(vv[cl + 1] * invv);
      pk[e2] = (uint32_t)__builtin_bit_cast(uint16_t, h0) |
               ((uint32_t)__builtin_bit_cast(uint16_t, h1) << 16);
    }
    int byteoff = j * 512 + ((cg * 128 + cb * 16) ^ ((j & 7) << 4));
    *reinterpret_cast<uint4*>(reinterpret_cast<char*>(lds) + byteoff) =
        make_uint4(pk[0], pk[1], pk[2], pk[3]);
  }
  __syncthreads();
#pragma unroll
  for (int rep = 0; rep < 8; ++rep) {
    int idx = rep * 256 + t;
    int jj = idx >> 5, cb = idx & 31;
    int byteoff = jj * 512 + ((cb * 16) ^ ((jj & 7) << 4));
    uint4 val = *reinterpret_cast<const uint4*>(
        reinterpret_cast<const char*>(lds) + byteoff);
    *reinterpret_cast<uint4*>(reinterpret_cast<char*>(dst) + jj * 512 + cb * 16) = val;
  }
}

// ---------------------------------------------------------------------------
// Level-0 x2 prep: normalize + f16 + transpose ALL x2_0 pixels:
// x2h[b][y][4+x][c] = x2[b][c][y][x] / (||x2[b,:,y,x]||+eps).
// Row stride 276 pixels; pixels [0..3] and [260..275] are zero pads.
// Block = (b, y, x-quarter). 3072 blocks. Body = xpose0 pattern.
// ---------------------------------------------------------------------------
__global__ __launch_bounds__(256) void xpose2_kernel(
    const float* __restrict__ x2, __fp16* __restrict__ x2h) {
  int bx = blockIdx.x;                        // 3072 = 4*192*4
  int q = bx & 3; int rem = bx >> 2;
  int y = rem % 192, b = rem / 192;
  char* rowb = (char*)x2h + (long)(b * 192 + y) * 276 * 512;  // 512 B/pixel
  char* dst = rowb + (long)(4 + 64 * q) * 512;
  __shared__ uint32_t lds[64 * 128];
  __shared__ float sred[4][64];
  int t = threadIdx.x;
  int j = t & 63, cg = t >> 6;
  const float* sp = x2 + (long)b * 12582912 + (long)y * 256 + 64 * q + j;
  float vv[64];
  float ss = 0.f;
#pragma unroll
  for (int c8 = 0; c8 < 64; ++c8) {
    float v = sp[(long)(cg * 64 + c8) * 49152];
    vv[c8] = v;
    ss += v * v;
  }
  sred[cg][j] = ss;
  __syncthreads();
  float invv = 1.f / (sqrtf(sred[0][j] + sred[1][j] + sred[2][j] + sred[3][j]) + EPSN);
#pragma unroll
  for (int cb = 0; cb < 8; ++cb) {
    uint32_t pk[4];
#pragma unroll
    for (int e2 = 0; e2 < 4; ++e2) {
      int cl = cb * 8 + e2 * 2;
      __fp16 h0 = (__fp16)(vv[cl] * invv);
      __fp16 h1 = (__fp16)(vv[cl + 1] * invv);
      pk[e2] = (uint32_t)__builtin_bit_cast(uint16_t, h0) |
               ((uint32_t)__builtin_bit_cast(uint16_t, h1) << 16);
    }
    int byteoff = j * 512 + ((cg * 128 + cb * 16) ^ ((j & 7) << 4));
    *reinterpret_cast<uint4*>(reinterpret_cast<char*>(lds) + byteoff) =
        make_uint4(pk[0], pk[1], pk[2], pk[3]);
  }
  __syncthreads();
#pragma unroll
  for (int rep = 0; rep < 8; ++rep) {
    int idx = rep * 256 + t;
    int jj = idx >> 5, cb = idx & 31;
    int byteoff = jj * 512 + ((cb * 16) ^ ((jj & 7) << 4));
    uint4 val = *reinterpret_cast<const uint4*>(
        reinterpret_cast<const char*>(lds) + byteoff);
    *reinterpret_cast<uint4*>(dst + jj * 512 + cb * 16) = val;
  }
  uint4 z = make_uint4(0, 0, 0, 0);
  if (q == 0 && t < 128)                      // left pad: pixels 0..3 = 2048 B
    *reinterpret_cast<uint4*>(rowb + t * 16) = z;
  if (q == 3) {                               // right pad: pixels 260..275 = 8192 B
    *reinterpret_cast<uint4*>(rowb + 133120 + t * 16) = z;
    *reinterpret_cast<uint4*>(rowb + 133120 + 4096 + t * 16) = z;
  }
}

// ---------------------------------------------------------------------------
// Level 0 via banded MFMA: block=(b,i,u), 1 wave. C[j][x] = sum_c
// x1h0[b,i,j,c] * x2h[b,y,x,c]; out[v,j] = C[j][4j+v-4] (norms folded,
// OOB x exactly 0 via pads). Fragment/C layout identical to corr1m (proven).
// Per j-tile (4): 5 x-tiles x 8 k-steps = 40 MFMA 16x16x32_f16.
// ---------------------------------------------------------------------------
__global__ __launch_bounds__(64) void corr0m_kernel(
    const __fp16* __restrict__ x1h, const __fp16* __restrict__ x2h,
    float* __restrict__ out) {
  int bx = blockIdx.x;
  int L = (bx & 7) * 216 + (bx >> 3);         // 1728 = 8 * 216 (bijective)
  int u = L % 9, i = (L / 9) % 48, b = L / 432;
  int y = 4 * i + u - 4;
  if (y < 0 || y >= 192) return;              // zfill0 covers these outputs
  int l = threadIdx.x, lm = l & 15, lk = l >> 4;
  const __fp16* A = x1h + (long)(b * 48 + i) * 16384;        // [j][c]
  const __fp16* B = x2h + (long)(b * 192 + y) * 70656;       // [x_idx][c], 276 rows
  __shared__ float c_lds[64][82];

#pragma unroll
  for (int jt = 0; jt < 4; ++jt) {
    f32x4 acc[5];
#pragma unroll
    for (int n = 0; n < 5; ++n) acc[n] = (f32x4)0.f;
    for (int ks = 0; ks < 8; ++ks) {
      int ko = ks * 32 + lk * 8;
      f16x8 af = __builtin_bit_cast(f16x8, *reinterpret_cast<const uint4*>(
                     A + (jt * 16 + lm) * 256 + ko));
#pragma unroll
      for (int n = 0; n < 5; ++n) {
        // B-tile rows: x_idx = 64*jt + 16*n + lm  (x_global = x_idx - 4)
        f16x8 bf = __builtin_bit_cast(f16x8, *reinterpret_cast<const uint4*>(
                       B + (long)(jt * 64 + n * 16 + lm) * 256 + ko));
        acc[n] = __builtin_amdgcn_mfma_f32_16x16x32_f16(af, bf, acc[n], 0, 0, 0);
      }
    }
#pragma unroll
    for (int n = 0; n < 5; ++n)
#pragma unroll
      for (int r = 0; r < 4; ++r)
        c_lds[jt * 16 + lk * 4 + r][n * 16 + lm] = acc[n][r];
  }
  LDS_FENCE();

  // band extract: out[b,0,u,v,i,j=l] = C[l][x_idx = 4l+v] (col = 4(l&15)+v)
  long ob = (long)b * 1741824 + (long)u * 27648 + (long)i * 64 + l;
#pragma unroll
  for (int v = 0; v < 9; ++v)
    out[ob + (long)v * 3072] = c_lds[l][4 * (l & 15) + v];
}

// ---------------------------------------------------------------------------
// Fallback level 0 (r15 passing kernel, raw f32 x1, shuffles) for small ws.
// ---------------------------------------------------------------------------
__global__ __launch_bounds__(256) void corr0_fb_kernel(
    const float* __restrict__ x1b, const float* __restrict__ x2,
    float* __restrict__ out) {
  int bx = blockIdx.x;
  int L = (bx & 7) * 96 + (bx >> 3);
  int y = L % 192, b = L / 192;
  int tid = threadIdx.x;
  int w = tid >> 6, lane = tid & 63;
  int i_lo = (y - 1) / 4; if (i_lo < 0) i_lo = 0;
  int i_hi = (y + 4) / 4; if (i_hi > 47) i_hi = 47;
  int NI = i_hi - i_lo + 1;
  __shared__ float red[4][34][64];
  __shared__ float inv2s[264];
  __shared__ float inv1s[3][64];
  float acc[3][9];
#pragma unroll
  for (int r = 0; r < 3; ++r)
#pragma unroll
    for (int v = 0; v < 9; ++v) acc[r][v] = 0.f;
  float sq0 = 0.f, sq1 = 0.f, sq2 = 0.f, sq3 = 0.f;
  float s1[3] = {0.f, 0.f, 0.f};
  const float* x2row = x2 + (long)b * 12582912 + (long)y * 256 + 4 * lane;
  const float* x1p[3];
#pragma unroll
  for (int r = 0; r < 3; ++r) {
    int ir = i_lo + r; if (ir > 47) ir = 47;
    x1p[r] = x1b + (long)b * 12582912 + (long)ir * 1024 + (long)lane * 4;
  }
#pragma unroll 4
  for (int cc = 0; cc < 64; ++cc) {
    int c = w * 64 + cc;
    long off = (long)c * 49152;
    float4 f = *reinterpret_cast<const float4*>(x2row + off);
    sq0 += f.x * f.x; sq1 += f.y * f.y; sq2 += f.z * f.z; sq3 += f.w * f.w;
#pragma unroll
    for (int r = 0; r < 3; ++r) {
      float xv = x1p[r][off];
      float xr = __shfl_down(xv, 1);
      float xl = __shfl_up(xv, 1);
      s1[r] += xv * xv;
      acc[r][0] += xr * f.x; acc[r][1] += xr * f.y;
      acc[r][2] += xr * f.z; acc[r][3] += xr * f.w;
      acc[r][4] += xv * f.x; acc[r][5] += xv * f.y;
      acc[r][6] += xv * f.z; acc[r][7] += xv * f.w;
      acc[r][8] += xl * f.x;
    }
  }
#pragma unroll
  for (int r = 0; r < 3; ++r) {
    red[w][r * 9 + 0][lane] = __shfl_up(acc[r][0], 1);
    red[w][r * 9 + 1][lane] = __shfl_up(acc[r][1], 1);
    red[w][r * 9 + 2][lane] = __shfl_up(acc[r][2], 1);
    red[w][r * 9 + 3][lane] = __shfl_up(acc[r][3], 1);
    red[w][r * 9 + 4][lane] = acc[r][4];
    red[w][r * 9 + 5][lane] = acc[r][5];
    red[w][r * 9 + 6][lane] = acc[r][6];
    red[w][r * 9 + 7][lane] = acc[r][7];
    red[w][r * 9 + 8][lane] = __shfl_down(acc[r][8], 1);
    red[w][31 + r][lane] = s1[r];
  }
  red[w][27][lane] = sq0; red[w][28][lane] = sq1;
  red[w][29][lane] = sq2; red[w][30][lane] = sq3;
  __syncthreads();
  {
    int comp = tid & 3, jj = tid >> 2;
    float ss = red[0][27 + comp][jj] + red[1][27 + comp][jj] +
               red[2][27 + comp][jj] + red[3][27 + comp][jj];
    inv2s[4 + tid] = 1.f / (sqrtf(ss) + EPSN);
    if (tid < 4) { inv2s[tid] = 0.f; inv2s[260 + tid] = 0.f; }
    if (tid < 192) {
      int r = tid >> 6, j = tid & 63;
      float t = red[0][31 + r][j] + red[1][31 + r][j] +
                red[2][31 + r][j] + red[3][31 + r][j];
      inv1s[r][j] = 1.f / (sqrtf(t) + EPSN);
    }
  }
  __syncthreads();
  int lim = NI * 576;
  for (int idx = tid; idx < lim; idx += 256) {
    int r = idx / 576, rem = idx - r * 576;
    int v = rem >> 6, j = rem & 63;
    int i_r = i_lo + r;
    int u_r = y - 4 * i_r + 4;
    float s = red[0][r * 9 + v][j] + red[1][r * 9 + v][j] +
              red[2][r * 9 + v][j] + red[3][r * 9 + v][j];
    out[(long)b * 1741824 + (long)u_r * 27648 + (long)v * 3072 + i_r * 64 + j] =
        s * inv1s[r][j] * inv2s[4 * j + v];
  }
}

// ---------------------------------------------------------------------------
// Zero-fill level-0 outputs with OOB x2 row: (i=0,u=0..3) and (i=47,u=8).
// ---------------------------------------------------------------------------
__global__ __launch_bounds__(256) void zfill0_kernel(float* __restrict__ out) {
  int idx = blockIdx.x * 256 + threadIdx.x;
  int b = idx / 2880, rem = idx - b * 2880;
  int k = rem / 576, rem2 = rem - k * 576;
  int v = rem2 >> 6, j = rem2 & 63;
  int u = (k < 4) ? k : 8;
  int i = (k < 4) ? 0 : 47;
  out[(long)b * 1741824 + (long)u * 27648 + (long)v * 3072 + i * 64 + j] = 0.f;
}

// ---------------------------------------------------------------------------
// Normalize + f16 + transpose level-1 tensors into ws (single-pass, passing).
// ---------------------------------------------------------------------------
__global__ __launch_bounds__(256) void xpose1_kernel(
    const float* __restrict__ x1, const float* __restrict__ x2,
    __fp16* __restrict__ o1, __fp16* __restrict__ o2) {
  int bx = blockIdx.x;                        // 384 = 2 * 4 * 48
  int tz = bx & 1; int rem = bx >> 1;
  int i = rem % 48, b = rem / 48;
  const float* src = tz ? x2 : x1;
  __fp16* dst = (tz ? o2 : o1) + (long)(b * 48 + i) * 16384;  // 64*256
  __shared__ uint32_t lds[64 * 128];
  __shared__ float sred[4][64];
  int t = threadIdx.x;
  int j = t & 63, cg = t >> 6;
  const float* sp = src + (long)b * 786432 + (long)i * 64 + j;
  float vv[64];
  float ss = 0.f;
#pragma unroll
  for (int c8 = 0; c8 < 64; ++c8) {
    float v = sp[(long)(cg * 64 + c8) * 3072];
    vv[c8] = v;
    ss += v * v;
  }
  sred[cg][j] = ss;
  __syncthreads();
  float invv = 1.f / (sqrtf(sred[0][j] + sred[1][j] + sred[2][j] + sred[3][j]) + EPSN);
#pragma unroll
  for (int cb = 0; cb < 8; ++cb) {
    uint32_t pk[4];
#pragma unroll
    for (int e2 = 0; e2 < 4; ++e2) {
      int cl = cb * 8 + e2 * 2;
      __fp16 h0 = (__fp16)(vv[cl] * invv);
      __fp16 h1 = (__fp16)(vv[cl + 1] * invv);
      pk[e2] = (uint32_t)__builtin_bit_cast(uint16_t, h0) |
               ((uint32_t)__builtin_bit_cast(uint16_t, h1) << 16);
    }
    int byteoff = j * 512 + ((cg * 128 + cb * 16) ^ ((j & 7) << 4));
    *reinterpret_cast<uint4*>(reinterpret_cast<char*>(lds) + byteoff) =
        make_uint4(pk[0], pk[1], pk[2], pk[3]);
  }
  __syncthreads();
#pragma unroll
  for (int rep = 0; rep < 8; ++rep) {
    int idx = rep * 256 + t;
    int jj = idx >> 5, cb = idx & 31;
    int byteoff = jj * 512 + ((cb * 16) ^ ((jj & 7) << 4));
    uint4 val = *reinterpret_cast<const uint4*>(
        reinterpret_cast<const char*>(lds) + byteoff);
    *reinterpret_cast<uint4*>(reinterpret_cast<char*>(dst) + jj * 512 + cb * 16) = val;
  }
}

// ---------------------------------------------------------------------------
// Level 1 via MFMA, zfill merged (unchanged, passing).
// ---------------------------------------------------------------------------
__device__ const int OFFS39[39] = {
    0, 1, -1, 2, -2, 3, -3, 4, -4, 5, -5, 6, -6, 8, -8, 9, -9, 10, -10,
    12, -12, 15, -15, 16, -16, 18, -18, 20, -20, 27, -27, 32, -32, 36, -36,
    48, -48, 64, -64};

__global__ __launch_bounds__(64) void corr1m_kernel(
    const __fp16* __restrict__ w1, const __fp16* __restrict__ w2,
    float* __restrict__ out) {
  const int dils[6] = {1, 2, 3, 5, 9, 16};
  int bx = blockIdx.x;
  int L = (bx & 7) * 936 + (bx >> 3);         // 7488 = 8 * 936 (bijective)
  int oi = L % 39, i = (L / 39) % 48, b = L / 1872;
  int o = OFFS39[oi];
  int y = i + o;
  bool valid = (y >= 0 && y < 48);
  int l = threadIdx.x;
  __shared__ float c_lds[64][65];

  if (valid) {
    int lm = l & 15, lk = l >> 4;
    const __fp16* A = w1 + (long)(b * 48 + i) * 16384;   // [j1][c]
    const __fp16* B = w2 + (long)(b * 48 + y) * 16384;   // [j2][c]
    f32x4 acc[4][4];
#pragma unroll
    for (int tm = 0; tm < 4; ++tm)
#pragma unroll
      for (int tn = 0; tn < 4; ++tn) acc[tm][tn] = (f32x4)0.f;

    for (int ks = 0; ks < 8; ++ks) {
      f16x8 af[4], bf[4];
      int ko = ks * 32 + lk * 8;
#pragma unroll
      for (int tm = 0; tm < 4; ++tm)
        af[tm] = __builtin_bit_cast(f16x8, *reinterpret_cast<const uint4*>(
                     A + (tm * 16 + lm) * 256 + ko));
#pragma unroll
      for (int tn = 0; tn < 4; ++tn)
        bf[tn] = __builtin_bit_cast(f16x8, *reinterpret_cast<const uint4*>(
                     B + (tn * 16 + lm) * 256 + ko));
#pragma unroll
      for (int tm = 0; tm < 4; ++tm)
#pragma unroll
        for (int tn = 0; tn < 4; ++tn)
          acc[tm][tn] = __builtin_amdgcn_mfma_f32_16x16x32_f16(
              af[tm], bf[tn], acc[tm][tn], 0, 0, 0);
    }
#pragma unroll
    for (int tm = 0; tm < 4; ++tm)
#pragma unroll
      for (int tn = 0; tn < 4; ++tn)
#pragma unroll
        for (int r = 0; r < 4; ++r)
          c_lds[tm * 16 + lk * 4 + r][tn * 16 + lm] = acc[tm][tn][r];
    LDS_FENCE();
  }

#pragma unroll
  for (int dI = 0; dI < 6; ++dI) {
    int d = dils[dI];
    if (o % d) continue;
    int ud = o / d;
    if (ud < -4 || ud > 4) continue;
    long ob = (long)b * 1741824 + (long)(1 + dI) * 248832 +
              (long)(ud + 4) * 27648 + (long)i * 64 + l;
#pragma unroll
    for (int v = 0; v < 9; ++v) {
      float val = 0.f;
      if (valid) {
        int j2 = l + (v - 4) * d;
        val = (j2 >= 0 && j2 < 64) ? c_lds[l][j2] : 0.f;
      }
      out[ob + (long)v * 3072] = val;
    }
  }
}

// ---------------------------------------------------------------------------
// Fallback level-1 (round-6 passing kernel) for small ws_size.
// ---------------------------------------------------------------------------
__global__ __launch_bounds__(64) void corr1_kernel(
    const float* __restrict__ x1, const float* __restrict__ x2,
    const float* __restrict__ ws, float* __restrict__ out) {
  int bx = blockIdx.x;
  int L = (bx & 7) * 1296 + (bx >> 3);
  int u = L % 9, dI = (L / 9) % 6, i = (L / 54) % 48, b = L / 2592;
  const int dils[6] = {1, 2, 3, 5, 9, 16};
  int d = dils[dI];
  int y = i + (u - 4) * d;
  int lane = threadIdx.x;
  long ob = (long)b * 1741824 + (long)(1 + dI) * 248832 + (long)u * 27648 +
            (long)i * 64 + lane;
  if (y < 0 || y >= 48) {
#pragma unroll
    for (int v = 0; v < 9; ++v) out[ob + v * 3072] = 0.f;
    return;
  }
  __shared__ uint4 x2t[192];
  x2t[lane] = make_uint4(0, 0, 0, 0);
  x2t[lane + 64] = make_uint4(0, 0, 0, 0);
  x2t[lane + 128] = make_uint4(0, 0, 0, 0);
  float acc[9];
#pragma unroll
  for (int v = 0; v < 9; ++v) acc[v] = 0.f;
  const float* x2row = x2 + (long)b * 786432 + (long)y * 64 + lane;
  const float* x1row = x1 + (long)b * 786432 + (long)i * 64 + lane;
#pragma unroll 1
  for (int cc8 = 0; cc8 < 32; ++cc8) {
    float x1v[8]; uint32_t xb[8];
#pragma unroll
    for (int cc = 0; cc < 8; ++cc) {
      long c = cc8 * 8 + cc;
      xb[cc] = __float_as_uint(x2row[c * 3072]) + 0x8000u;
      x1v[cc] = x1row[c * 3072];
    }
    uint4 pk;
    pk.x = (xb[0] >> 16) | (xb[1] & 0xffff0000u);
    pk.y = (xb[2] >> 16) | (xb[3] & 0xffff0000u);
    pk.z = (xb[4] >> 16) | (xb[5] & 0xffff0000u);
    pk.w = (xb[6] >> 16) | (xb[7] & 0xffff0000u);
    x2t[64 + lane] = pk;
    LDS_FENCE();
#pragma unroll
    for (int v = 0; v < 9; ++v) {
      uint4 q = x2t[64 + lane + (v - 4) * d];
      float s;
      s  = x1v[0] * __uint_as_float(q.x << 16);
      s += x1v[1] * __uint_as_float(q.x & 0xffff0000u);
      s += x1v[2] * __uint_as_float(q.y << 16);
      s += x1v[3] * __uint_as_float(q.y & 0xffff0000u);
      s += x1v[4] * __uint_as_float(q.z << 16);
      s += x1v[5] * __uint_as_float(q.z & 0xffff0000u);
      s += x1v[6] * __uint_as_float(q.w << 16);
      s += x1v[7] * __uint_as_float(q.w & 0xffff0000u);
      acc[v] += s;
    }
    LDS_FENCE();
  }
  const float* i1 = ws + b * 3072 + i * 64;
  const float* i2 = ws + 12288 + b * 3072 + y * 64;
  float inv1 = i1[lane];
#pragma unroll
  for (int v = 0; v < 9; ++v) {
    int col = lane + (v - 4) * d;
    float i2v = (col >= 0 && col < 64) ? i2[col] : 0.f;
    out[ob + v * 3072] = acc[v] * inv1 * i2v;
  }
}

extern "C" void kernel_launch(void* const* d_in, const int* in_sizes, int n_in,
                              void* d_out, int out_size, void* d_ws, size_t ws_size,
                              hipStream_t stream) {
  const float* x1_0 = (const float*)d_in[0];
  const float* x1_1 = (const float*)d_in[1];
  const float* x2_0 = (const float*)d_in[2];
  const float* x2_1 = (const float*)d_in[3];
  float* out = (float*)d_out;
  float* ws = (float*)d_ws;
  if (ws_size >= 127500288) {
    __fp16* x1h0 = (__fp16*)((char*)d_ws + 12681216);
    __fp16* x2h0 = (__fp16*)((char*)d_ws + 18972672);
    xpose0_kernel<<<192, 256, 0, stream>>>(x1_0, x1h0);
    xpose2_kernel<<<3072, 256, 0, stream>>>(x2_0, x2h0);
    corr0m_kernel<<<1728, 64, 0, stream>>>(x1h0, x2h0, out);
  } else {
    corr0_fb_kernel<<<768, 256, 0, stream>>>(x1_0, x2_0, out);
  }
  zfill0_kernel<<<45, 256, 0, stream>>>(out);
  if (ws_size >= 12681216) {
    __fp16* w1h = (__fp16*)((char*)d_ws + 98304);
    __fp16* w2h = w1h + 3145728;              // 4*48*64*256 elems
    xpose1_kernel<<<384, 256, 0, stream>>>(x1_1, x2_1, w1h, w2h);
    corr1m_kernel<<<7488, 64, 0, stream>>>(w1h, w2h, out);
  } else {
    norms1_kernel<<<96, 256, 0, stream>>>(x1_1, x2_1, ws);
    corr1_kernel<<<10368, 64, 0, stream>>>(x1_1, x2_1, ws, out);
  }
}

// Round 19
// 160.811 us; speedup vs baseline: 1.0506x; 1.0506x over previous
//
#include <hip/hip_runtime.h>
#include <stdint.h>

#define EPSN 1e-9f

typedef __fp16 f16x8 __attribute__((ext_vector_type(8)));
typedef float f32x4 __attribute__((ext_vector_type(4)));

// Wave-level LDS fence (rule #18: sched_barrier after waitcnt).
#define LDS_FENCE()                                        \
  do {                                                     \
    asm volatile("s_waitcnt lgkmcnt(0)" ::: "memory");     \
    __builtin_amdgcn_sched_barrier(0);                     \
  } while (0)

// ---------------------------------------------------------------------------
// ws layout (bytes):
//   [0)        inv1_1/inv2_1 f32 (fallback path)        98304
//   [98304)    w1h  [4][48][64][256] f16                6291456
//   [6389760)  w2h  same                                6291456
//   [12681216) x1s  [4][256][48][64] f32 (dense gather) 12582912
//   fast path needs 25264128 B.
// ---------------------------------------------------------------------------

__global__ __launch_bounds__(256) void norms1_kernel(
    const float* __restrict__ x1_1, const float* __restrict__ x2_1,
    float* __restrict__ ws) {
  int p = blockIdx.x * 256 + threadIdx.x;     // 24576 total
  const float* src = (p < 12288) ? x1_1 : x2_1;
  int q = (p < 12288) ? p : p - 12288;        // 12288 is NOT pow2
  long base = (long)(q / 3072) * 786432 + (q % 3072);
  float ss = 0.f;
#pragma unroll 8
  for (int c = 0; c < 256; ++c) { float v = src[base + (long)c * 3072]; ss += v * v; }
  ws[p] = 1.f / (sqrtf(ss) + EPSN);
}

// ---------------------------------------------------------------------------
// Dense gather of level-0 x1 strided pixels: x1s[b][c][i][j] = x1[b][c][4i][4j].
// ---------------------------------------------------------------------------
__global__ __launch_bounds__(256) void gather1_kernel(
    const float* __restrict__ x1, float* __restrict__ x1s) {
  int idx = blockIdx.x * 256 + threadIdx.x;   // 12288 * 256 = 3145728 exactly
  int j = idx & 63;
  int i = (idx >> 6) % 48;
  int c = ((idx >> 6) / 48) & 255;
  int b = idx / 786432;
  x1s[idx] = x1[(long)b * 12582912 + (long)c * 49152 + (long)(4 * i) * 256 + 4 * j];
}

// ---------------------------------------------------------------------------
// Normalize + f16 + transpose level-1 tensors into ws (single-pass, passing).
// ---------------------------------------------------------------------------
__global__ __launch_bounds__(256) void xpose1_kernel(
    const float* __restrict__ x1, const float* __restrict__ x2,
    __fp16* __restrict__ o1, __fp16* __restrict__ o2) {
  int bx = blockIdx.x;                        // 384 = 2 * 4 * 48
  int tz = bx & 1; int rem = bx >> 1;
  int i = rem % 48, b = rem / 48;
  const float* src = tz ? x2 : x1;
  __fp16* dst = (tz ? o2 : o1) + (long)(b * 48 + i) * 16384;  // 64*256
  __shared__ uint32_t lds[64 * 128];
  __shared__ float sred[4][64];
  int t = threadIdx.x;
  int j = t & 63, cg = t >> 6;
  const float* sp = src + (long)b * 786432 + (long)i * 64 + j;
  float vv[64];
  float ss = 0.f;
#pragma unroll
  for (int c8 = 0; c8 < 64; ++c8) {
    float v = sp[(long)(cg * 64 + c8) * 3072];
    vv[c8] = v;
    ss += v * v;
  }
  sred[cg][j] = ss;
  __syncthreads();
  float invv = 1.f / (sqrtf(sred[0][j] + sred[1][j] + sred[2][j] + sred[3][j]) + EPSN);
#pragma unroll
  for (int cb = 0; cb < 8; ++cb) {
    uint32_t pk[4];
#pragma unroll
    for (int e2 = 0; e2 < 4; ++e2) {
      int cl = cb * 8 + e2 * 2;
      __fp16 h0 = (__fp16)(vv[cl] * invv);
      __fp16 h1 = (__fp16)(vv[cl + 1] * invv);
      pk[e2] = (uint32_t)__builtin_bit_cast(uint16_t, h0) |
               ((uint32_t)__builtin_bit_cast(uint16_t, h1) << 16);
    }
    int byteoff = j * 512 + ((cg * 128 + cb * 16) ^ ((j & 7) << 4));
    *reinterpret_cast<uint4*>(reinterpret_cast<char*>(lds) + byteoff) =
        make_uint4(pk[0], pk[1], pk[2], pk[3]);
  }
  __syncthreads();
#pragma unroll
  for (int rep = 0; rep < 8; ++rep) {
    int idx = rep * 256 + t;
    int jj = idx >> 5, cb = idx & 31;
    int byteoff = jj * 512 + ((cb * 16) ^ ((jj & 7) << 4));
    uint4 val = *reinterpret_cast<const uint4*>(
        reinterpret_cast<const char*>(lds) + byteoff);
    *reinterpret_cast<uint4*>(reinterpret_cast<char*>(dst) + jj * 512 + cb * 16) = val;
  }
}

// ---------------------------------------------------------------------------
// FUSED corr kernel: block segments (dispatch order = overlap):
//   [0, 768):      corr0 (r15-proven shuffle (b,y) kernel, dense x1s)
//   [768, 8256):   corr1m as 4-wave tm-split (same MFMA math as r8-proven)
//   [8256, 8301):  zfill0 (level-0 OOB-row zero outputs)
// Shared-LDS union: 9160 floats (corr0's red+inv2s+inv1s; corr1m's c_lds).
// ---------------------------------------------------------------------------
__device__ const int OFFS39[39] = {
    0, 1, -1, 2, -2, 3, -3, 4, -4, 5, -5, 6, -6, 8, -8, 9, -9, 10, -10,
    12, -12, 15, -15, 16, -16, 18, -18, 20, -20, 27, -27, 32, -32, 36, -36,
    48, -48, 64, -64};

__global__ __launch_bounds__(256) void corr_fused_kernel(
    const float* __restrict__ x1s, const float* __restrict__ x2,
    const __fp16* __restrict__ w1h, const __fp16* __restrict__ w2h,
    float* __restrict__ out) {
  __shared__ float smem[9160];                // 36640 B union
  int bxg = blockIdx.x;
  int tid = threadIdx.x;

  if (bxg < 768) {
    // ---------------- segment A: corr0 (r15 body, verbatim math) ----------
    int L = (bxg & 7) * 96 + (bxg >> 3);      // 768 = 8 * 96 (bijective)
    int y = L % 192, b = L / 192;
    int w = tid >> 6, lane = tid & 63;
    int i_lo = (y - 1) / 4; if (i_lo < 0) i_lo = 0;
    int i_hi = (y + 4) / 4; if (i_hi > 47) i_hi = 47;
    int NI = i_hi - i_lo + 1;                 // 1..3
    float (*red)[34][64] = reinterpret_cast<float(*)[34][64]>(smem);
    float* inv2s = smem + 8704;               // [264]; pads zeroed below
    float (*inv1s)[64] = reinterpret_cast<float(*)[64]>(smem + 8968);

    float acc[3][9];
#pragma unroll
    for (int r = 0; r < 3; ++r)
#pragma unroll
      for (int v = 0; v < 9; ++v) acc[r][v] = 0.f;
    float sq0 = 0.f, sq1 = 0.f, sq2 = 0.f, sq3 = 0.f;
    float s1[3] = {0.f, 0.f, 0.f};

    const float* x2row = x2 + (long)b * 12582912 + (long)y * 256 + 4 * lane;
    const float* x1p[3];
#pragma unroll
    for (int r = 0; r < 3; ++r) {
      int ir = i_lo + r; if (ir > 47) ir = 47;
      x1p[r] = x1s + (long)b * 786432 + (long)ir * 64 + lane;
    }

#pragma unroll 4
    for (int cc = 0; cc < 64; ++cc) {
      int c = w * 64 + cc;
      float4 f = *reinterpret_cast<const float4*>(x2row + (long)c * 49152);
      long off1 = (long)c * 3072;
      sq0 += f.x * f.x; sq1 += f.y * f.y; sq2 += f.z * f.z; sq3 += f.w * f.w;
#pragma unroll
      for (int r = 0; r < 3; ++r) {
        float xv = x1p[r][off1];
        float xr = __shfl_down(xv, 1);
        float xl = __shfl_up(xv, 1);
        s1[r] += xv * xv;
        acc[r][0] += xr * f.x; acc[r][1] += xr * f.y;
        acc[r][2] += xr * f.z; acc[r][3] += xr * f.w;
        acc[r][4] += xv * f.x; acc[r][5] += xv * f.y;
        acc[r][6] += xv * f.z; acc[r][7] += xv * f.w;
        acc[r][8] += xl * f.x;
      }
    }

#pragma unroll
    for (int r = 0; r < 3; ++r) {
      red[w][r * 9 + 0][lane] = __shfl_up(acc[r][0], 1);
      red[w][r * 9 + 1][lane] = __shfl_up(acc[r][1], 1);
      red[w][r * 9 + 2][lane] = __shfl_up(acc[r][2], 1);
      red[w][r * 9 + 3][lane] = __shfl_up(acc[r][3], 1);
      red[w][r * 9 + 4][lane] = acc[r][4];
      red[w][r * 9 + 5][lane] = acc[r][5];
      red[w][r * 9 + 6][lane] = acc[r][6];
      red[w][r * 9 + 7][lane] = acc[r][7];
      red[w][r * 9 + 8][lane] = __shfl_down(acc[r][8], 1);
      red[w][31 + r][lane] = s1[r];
    }
    red[w][27][lane] = sq0; red[w][28][lane] = sq1;
    red[w][29][lane] = sq2; red[w][30][lane] = sq3;
    __syncthreads();
    {
      int comp = tid & 3, jj = tid >> 2;
      float ss = red[0][27 + comp][jj] + red[1][27 + comp][jj] +
                 red[2][27 + comp][jj] + red[3][27 + comp][jj];
      inv2s[4 + tid] = 1.f / (sqrtf(ss) + EPSN);
      if (tid < 4) { inv2s[tid] = 0.f; inv2s[260 + tid] = 0.f; }
      if (tid < 192) {
        int r = tid >> 6, j = tid & 63;
        float t = red[0][31 + r][j] + red[1][31 + r][j] +
                  red[2][31 + r][j] + red[3][31 + r][j];
        inv1s[r][j] = 1.f / (sqrtf(t) + EPSN);
      }
    }
    __syncthreads();
    int lim = NI * 576;
    for (int idx = tid; idx < lim; idx += 256) {
      int r = idx / 576, rem = idx - r * 576;
      int v = rem >> 6, j = rem & 63;
      int i_r = i_lo + r;
      int u_r = y - 4 * i_r + 4;
      float s = red[0][r * 9 + v][j] + red[1][r * 9 + v][j] +
                red[2][r * 9 + v][j] + red[3][r * 9 + v][j];
      out[(long)b * 1741824 + (long)u_r * 27648 + (long)v * 3072 + i_r * 64 + j] =
          s * inv1s[r][j] * inv2s[4 * j + v];
    }
  } else if (bxg < 8256) {
    // ---------------- segment B: corr1m, 4-wave tm-split -------------------
    const int dils[6] = {1, 2, 3, 5, 9, 16};
    int s = bxg - 768;
    int L = (s & 7) * 936 + (s >> 3);         // 7488 = 8 * 936 (bijective)
    int oi = L % 39, i = (L / 39) % 48, b = L / 1872;
    int o = OFFS39[oi];
    int y = i + o;
    bool valid = (y >= 0 && y < 48);
    int l = tid & 63, w = tid >> 6;
    float (*c_lds)[65] = reinterpret_cast<float(*)[65]>(smem);

    if (valid) {
      int lm = l & 15, lk = l >> 4;
      const __fp16* A = w1h + (long)(b * 48 + i) * 16384;   // [j1][c]
      const __fp16* B = w2h + (long)(b * 48 + y) * 16384;   // [j2][c]
      f32x4 acc[4];
#pragma unroll
      for (int tn = 0; tn < 4; ++tn) acc[tn] = (f32x4)0.f;
      for (int ks = 0; ks < 8; ++ks) {
        int ko = ks * 32 + lk * 8;
        f16x8 af = __builtin_bit_cast(f16x8, *reinterpret_cast<const uint4*>(
                       A + (w * 16 + lm) * 256 + ko));       // tm = w
#pragma unroll
        for (int tn = 0; tn < 4; ++tn) {
          f16x8 bf = __builtin_bit_cast(f16x8, *reinterpret_cast<const uint4*>(
                         B + (tn * 16 + lm) * 256 + ko));
          acc[tn] = __builtin_amdgcn_mfma_f32_16x16x32_f16(af, bf, acc[tn], 0, 0, 0);
        }
      }
#pragma unroll
      for (int tn = 0; tn < 4; ++tn)
#pragma unroll
        for (int r = 0; r < 4; ++r)
          c_lds[w * 16 + lk * 4 + r][tn * 16 + lm] = acc[tn][r];
    }
    __syncthreads();

    if (tid < 64) {
#pragma unroll
      for (int dI = 0; dI < 6; ++dI) {
        int d = dils[dI];
        if (o % d) continue;
        int ud = o / d;
        if (ud < -4 || ud > 4) continue;
        long ob = (long)b * 1741824 + (long)(1 + dI) * 248832 +
                  (long)(ud + 4) * 27648 + (long)i * 64 + l;
#pragma unroll
        for (int v = 0; v < 9; ++v) {
          float val = 0.f;
          if (valid) {
            int j2 = l + (v - 4) * d;
            val = (j2 >= 0 && j2 < 64) ? c_lds[l][j2] : 0.f;
          }
          out[ob + (long)v * 3072] = val;
        }
      }
    }
  } else {
    // ---------------- segment C: zfill0 -----------------------------------
    int idx = (bxg - 8256) * 256 + tid;       // 45 * 256 = 11520 exactly
    int b = idx / 2880, rem = idx - b * 2880;
    int k = rem / 576, rem2 = rem - k * 576;
    int v = rem2 >> 6, j = rem2 & 63;
    int u = (k < 4) ? k : 8;
    int i = (k < 4) ? 0 : 47;
    out[(long)b * 1741824 + (long)u * 27648 + (long)v * 3072 + i * 64 + j] = 0.f;
  }
}

// ---------------------------------------------------------------------------
// Fallback level 0 (r15 passing kernel, raw f32 x1, shuffles) for small ws.
// ---------------------------------------------------------------------------
__global__ __launch_bounds__(256) void corr0_fb_kernel(
    const float* __restrict__ x1b, const float* __restrict__ x2,
    float* __restrict__ out) {
  int bx = blockIdx.x;
  int L = (bx & 7) * 96 + (bx >> 3);
  int y = L % 192, b = L / 192;
  int tid = threadIdx.x;
  int w = tid >> 6, lane = tid & 63;
  int i_lo = (y - 1) / 4; if (i_lo < 0) i_lo = 0;
  int i_hi = (y + 4) / 4; if (i_hi > 47) i_hi = 47;
  int NI = i_hi - i_lo + 1;
  __shared__ float red[4][34][64];
  __shared__ float inv2s[264];
  __shared__ float inv1s[3][64];
  float acc[3][9];
#pragma unroll
  for (int r = 0; r < 3; ++r)
#pragma unroll
    for (int v = 0; v < 9; ++v) acc[r][v] = 0.f;
  float sq0 = 0.f, sq1 = 0.f, sq2 = 0.f, sq3 = 0.f;
  float s1[3] = {0.f, 0.f, 0.f};
  const float* x2row = x2 + (long)b * 12582912 + (long)y * 256 + 4 * lane;
  const float* x1p[3];
#pragma unroll
  for (int r = 0; r < 3; ++r) {
    int ir = i_lo + r; if (ir > 47) ir = 47;
    x1p[r] = x1b + (long)b * 12582912 + (long)ir * 1024 + (long)lane * 4;
  }
#pragma unroll 4
  for (int cc = 0; cc < 64; ++cc) {
    int c = w * 64 + cc;
    long off = (long)c * 49152;
    float4 f = *reinterpret_cast<const float4*>(x2row + off);
    sq0 += f.x * f.x; sq1 += f.y * f.y; sq2 += f.z * f.z; sq3 += f.w * f.w;
#pragma unroll
    for (int r = 0; r < 3; ++r) {
      float xv = x1p[r][off];
      float xr = __shfl_down(xv, 1);
      float xl = __shfl_up(xv, 1);
      s1[r] += xv * xv;
      acc[r][0] += xr * f.x; acc[r][1] += xr * f.y;
      acc[r][2] += xr * f.z; acc[r][3] += xr * f.w;
      acc[r][4] += xv * f.x; acc[r][5] += xv * f.y;
      acc[r][6] += xv * f.z; acc[r][7] += xv * f.w;
      acc[r][8] += xl * f.x;
    }
  }
#pragma unroll
  for (int r = 0; r < 3; ++r) {
    red[w][r * 9 + 0][lane] = __shfl_up(acc[r][0], 1);
    red[w][r * 9 + 1][lane] = __shfl_up(acc[r][1], 1);
    red[w][r * 9 + 2][lane] = __shfl_up(acc[r][2], 1);
    red[w][r * 9 + 3][lane] = __shfl_up(acc[r][3], 1);
    red[w][r * 9 + 4][lane] = acc[r][4];
    red[w][r * 9 + 5][lane] = acc[r][5];
    red[w][r * 9 + 6][lane] = acc[r][6];
    red[w][r * 9 + 7][lane] = acc[r][7];
    red[w][r * 9 + 8][lane] = __shfl_down(acc[r][8], 1);
    red[w][31 + r][lane] = s1[r];
  }
  red[w][27][lane] = sq0; red[w][28][lane] = sq1;
  red[w][29][lane] = sq2; red[w][30][lane] = sq3;
  __syncthreads();
  {
    int comp = tid & 3, jj = tid >> 2;
    float ss = red[0][27 + comp][jj] + red[1][27 + comp][jj] +
               red[2][27 + comp][jj] + red[3][27 + comp][jj];
    inv2s[4 + tid] = 1.f / (sqrtf(ss) + EPSN);
    if (tid < 4) { inv2s[tid] = 0.f; inv2s[260 + tid] = 0.f; }
    if (tid < 192) {
      int r = tid >> 6, j = tid & 63;
      float t = red[0][31 + r][j] + red[1][31 + r][j] +
                red[2][31 + r][j] + red[3][31 + r][j];
      inv1s[r][j] = 1.f / (sqrtf(t) + EPSN);
    }
  }
  __syncthreads();
  int lim = NI * 576;
  for (int idx = tid; idx < lim; idx += 256) {
    int r = idx / 576, rem = idx - r * 576;
    int v = rem >> 6, j = rem & 63;
    int i_r = i_lo + r;
    int u_r = y - 4 * i_r + 4;
    float s = red[0][r * 9 + v][j] + red[1][r * 9 + v][j] +
              red[2][r * 9 + v][j] + red[3][r * 9 + v][j];
    out[(long)b * 1741824 + (long)u_r * 27648 + (long)v * 3072 + i_r * 64 + j] =
        s * inv1s[r][j] * inv2s[4 * j + v];
  }
}

__global__ __launch_bounds__(256) void zfill0_kernel(float* __restrict__ out) {
  int idx = blockIdx.x * 256 + threadIdx.x;
  int b = idx / 2880, rem = idx - b * 2880;
  int k = rem / 576, rem2 = rem - k * 576;
  int v = rem2 >> 6, j = rem2 & 63;
  int u = (k < 4) ? k : 8;
  int i = (k < 4) ? 0 : 47;
  out[(long)b * 1741824 + (long)u * 27648 + (long)v * 3072 + i * 64 + j] = 0.f;
}

// ---------------------------------------------------------------------------
// Level 1 via MFMA, 64-thread standalone (mid-path fallback; r8-proven).
// ---------------------------------------------------------------------------
__global__ __launch_bounds__(64) void corr1m_kernel(
    const __fp16* __restrict__ w1, const __fp16* __restrict__ w2,
    float* __restrict__ out) {
  const int dils[6] = {1, 2, 3, 5, 9, 16};
  int bx = blockIdx.x;
  int L = (bx & 7) * 936 + (bx >> 3);
  int oi = L % 39, i = (L / 39) % 48, b = L / 1872;
  int o = OFFS39[oi];
  int y = i + o;
  bool valid = (y >= 0 && y < 48);
  int l = threadIdx.x;
  __shared__ float c_lds[64][65];
  if (valid) {
    int lm = l & 15, lk = l >> 4;
    const __fp16* A = w1 + (long)(b * 48 + i) * 16384;
    const __fp16* B = w2 + (long)(b * 48 + y) * 16384;
    f32x4 acc[4][4];
#pragma unroll
    for (int tm = 0; tm < 4; ++tm)
#pragma unroll
      for (int tn = 0; tn < 4; ++tn) acc[tm][tn] = (f32x4)0.f;
    for (int ks = 0; ks < 8; ++ks) {
      f16x8 af[4], bf[4];
      int ko = ks * 32 + lk * 8;
#pragma unroll
      for (int tm = 0; tm < 4; ++tm)
        af[tm] = __builtin_bit_cast(f16x8, *reinterpret_cast<const uint4*>(
                     A + (tm * 16 + lm) * 256 + ko));
#pragma unroll
      for (int tn = 0; tn < 4; ++tn)
        bf[tn] = __builtin_bit_cast(f16x8, *reinterpret_cast<const uint4*>(
                     B + (tn * 16 + lm) * 256 + ko));
#pragma unroll
      for (int tm = 0; tm < 4; ++tm)
#pragma unroll
        for (int tn = 0; tn < 4; ++tn)
          acc[tm][tn] = __builtin_amdgcn_mfma_f32_16x16x32_f16(
              af[tm], bf[tn], acc[tm][tn], 0, 0, 0);
    }
#pragma unroll
    for (int tm = 0; tm < 4; ++tm)
#pragma unroll
      for (int tn = 0; tn < 4; ++tn)
#pragma unroll
        for (int r = 0; r < 4; ++r)
          c_lds[tm * 16 + lk * 4 + r][tn * 16 + lm] = acc[tm][tn][r];
    LDS_FENCE();
  }
#pragma unroll
  for (int dI = 0; dI < 6; ++dI) {
    int d = dils[dI];
    if (o % d) continue;
    int ud = o / d;
    if (ud < -4 || ud > 4) continue;
    long ob = (long)b * 1741824 + (long)(1 + dI) * 248832 +
              (long)(ud + 4) * 27648 + (long)i * 64 + l;
#pragma unroll
    for (int v = 0; v < 9; ++v) {
      float val = 0.f;
      if (valid) {
        int j2 = l + (v - 4) * d;
        val = (j2 >= 0 && j2 < 64) ? c_lds[l][j2] : 0.f;
      }
      out[ob + (long)v * 3072] = val;
    }
  }
}

// ---------------------------------------------------------------------------
// Fallback level-1 (round-6 passing kernel) for small ws_size.
// ---------------------------------------------------------------------------
__global__ __launch_bounds__(64) void corr1_kernel(
    const float* __restrict__ x1, const float* __restrict__ x2,
    const float* __restrict__ ws, float* __restrict__ out) {
  int bx = blockIdx.x;
  int L = (bx & 7) * 1296 + (bx >> 3);
  int u = L % 9, dI = (L / 9) % 6, i = (L / 54) % 48, b = L / 2592;
  const int dils[6] = {1, 2, 3, 5, 9, 16};
  int d = dils[dI];
  int y = i + (u - 4) * d;
  int lane = threadIdx.x;
  long ob = (long)b * 1741824 + (long)(1 + dI) * 248832 + (long)u * 27648 +
            (long)i * 64 + lane;
  if (y < 0 || y >= 48) {
#pragma unroll
    for (int v = 0; v < 9; ++v) out[ob + v * 3072] = 0.f;
    return;
  }
  __shared__ uint4 x2t[192];
  x2t[lane] = make_uint4(0, 0, 0, 0);
  x2t[lane + 64] = make_uint4(0, 0, 0, 0);
  x2t[lane + 128] = make_uint4(0, 0, 0, 0);
  float acc[9];
#pragma unroll
  for (int v = 0; v < 9; ++v) acc[v] = 0.f;
  const float* x2row = x2 + (long)b * 786432 + (long)y * 64 + lane;
  const float* x1row = x1 + (long)b * 786432 + (long)i * 64 + lane;
#pragma unroll 1
  for (int cc8 = 0; cc8 < 32; ++cc8) {
    float x1v[8]; uint32_t xb[8];
#pragma unroll
    for (int cc = 0; cc < 8; ++cc) {
      long c = cc8 * 8 + cc;
      xb[cc] = __float_as_uint(x2row[c * 3072]) + 0x8000u;
      x1v[cc] = x1row[c * 3072];
    }
    uint4 pk;
    pk.x = (xb[0] >> 16) | (xb[1] & 0xffff0000u);
    pk.y = (xb[2] >> 16) | (xb[3] & 0xffff0000u);
    pk.z = (xb[4] >> 16) | (xb[5] & 0xffff0000u);
    pk.w = (xb[6] >> 16) | (xb[7] & 0xffff0000u);
    x2t[64 + lane] = pk;
    LDS_FENCE();
#pragma unroll
    for (int v = 0; v < 9; ++v) {
      uint4 q = x2t[64 + lane + (v - 4) * d];
      float s;
      s  = x1v[0] * __uint_as_float(q.x << 16);
      s += x1v[1] * __uint_as_float(q.x & 0xffff0000u);
      s += x1v[2] * __uint_as_float(q.y << 16);
      s += x1v[3] * __uint_as_float(q.y & 0xffff0000u);
      s += x1v[4] * __uint_as_float(q.z << 16);
      s += x1v[5] * __uint_as_float(q.z & 0xffff0000u);
      s += x1v[6] * __uint_as_float(q.w << 16);
      s += x1v[7] * __uint_as_float(q.w & 0xffff0000u);
      acc[v] += s;
    }
    LDS_FENCE();
  }
  const float* i1 = ws + b * 3072 + i * 64;
  const float* i2 = ws + 12288 + b * 3072 + y * 64;
  float inv1 = i1[lane];
#pragma unroll
  for (int v = 0; v < 9; ++v) {
    int col = lane + (v - 4) * d;
    float i2v = (col >= 0 && col < 64) ? i2[col] : 0.f;
    out[ob + v * 3072] = acc[v] * inv1 * i2v;
  }
}

extern "C" void kernel_launch(void* const* d_in, const int* in_sizes, int n_in,
                              void* d_out, int out_size, void* d_ws, size_t ws_size,
                              hipStream_t stream) {
  const float* x1_0 = (const float*)d_in[0];
  const float* x1_1 = (const float*)d_in[1];
  const float* x2_0 = (const float*)d_in[2];
  const float* x2_1 = (const float*)d_in[3];
  float* out = (float*)d_out;
  float* ws = (float*)d_ws;
  if (ws_size >= 25264128) {
    __fp16* w1h = (__fp16*)((char*)d_ws + 98304);
    __fp16* w2h = w1h + 3145728;
    float* x1s = (float*)((char*)d_ws + 12681216);
    gather1_kernel<<<12288, 256, 0, stream>>>(x1_0, x1s);
    xpose1_kernel<<<384, 256, 0, stream>>>(x1_1, x2_1, w1h, w2h);
    corr_fused_kernel<<<8301, 256, 0, stream>>>(x1s, x2_0, w1h, w2h, out);
  } else if (ws_size >= 12681216) {
    __fp16* w1h = (__fp16*)((char*)d_ws + 98304);
    __fp16* w2h = w1h + 3145728;
    corr0_fb_kernel<<<768, 256, 0, stream>>>(x1_0, x2_0, out);
    zfill0_kernel<<<45, 256, 0, stream>>>(out);
    xpose1_kernel<<<384, 256, 0, stream>>>(x1_1, x2_1, w1h, w2h);
    corr1m_kernel<<<7488, 64, 0, stream>>>(w1h, w2h, out);
  } else {
    corr0_fb_kernel<<<768, 256, 0, stream>>>(x1_0, x2_0, out);
    zfill0_kernel<<<45, 256, 0, stream>>>(out);
    norms1_kernel<<<96, 256, 0, stream>>>(x1_1, x2_1, ws);
    corr1_kernel<<<10368, 64, 0, stream>>>(x1_1, x2_1, ws, out);
  }
}

// Round 20
// 116.820 us; speedup vs baseline: 1.4462x; 1.3766x over previous
//
#include <hip/hip_runtime.h>
#include <stdint.h>

#define EPSN 1e-9f

typedef __fp16 f16x8 __attribute__((ext_vector_type(8)));
typedef float f32x4 __attribute__((ext_vector_type(4)));

// Wave-level LDS fence (rule #18: sched_barrier after waitcnt).
#define LDS_FENCE()                                        \
  do {                                                     \
    asm volatile("s_waitcnt lgkmcnt(0)" ::: "memory");     \
    __builtin_amdgcn_sched_barrier(0);                     \
  } while (0)

// ---------------------------------------------------------------------------
// ws layout (bytes):
//   [0)        inv1_1/inv2_1 f32 (fallback path)        98304 B
//   [98304)    w1h  [4][48][64][256] f16                6291456 B
//   [6389760)  w2h  same                                6291456 B
//   [12681216) x1s  [4][256][48][64] f32 (dense gather) 12582912 B
//   full fast path needs 25264128 B.
// ---------------------------------------------------------------------------

__global__ __launch_bounds__(256) void norms1_kernel(
    const float* __restrict__ x1_1, const float* __restrict__ x2_1,
    float* __restrict__ ws) {
  int p = blockIdx.x * 256 + threadIdx.x;     // 24576 total
  const float* src = (p < 12288) ? x1_1 : x2_1;
  int q = (p < 12288) ? p : p - 12288;        // 12288 is NOT pow2
  long base = (long)(q / 3072) * 786432 + (q % 3072);
  float ss = 0.f;
#pragma unroll 8
  for (int c = 0; c < 256; ++c) { float v = src[base + (long)c * 3072]; ss += v * v; }
  ws[p] = 1.f / (sqrtf(ss) + EPSN);
}

// ---------------------------------------------------------------------------
// Dense gather of level-0 x1 strided pixels: x1s[b][c][i][j] = x1[b][c][4i][4j].
// ---------------------------------------------------------------------------
__global__ __launch_bounds__(256) void gather1_kernel(
    const float* __restrict__ x1, float* __restrict__ x1s) {
  int idx = blockIdx.x * 256 + threadIdx.x;   // 12288 * 256 = 3145728 exactly
  int j = idx & 63;
  int i = (idx >> 6) % 48;
  int c = ((idx >> 6) / 48) & 255;
  int b = idx / 786432;
  x1s[idx] = x1[(long)b * 12582912 + (long)c * 49152 + (long)(4 * i) * 256 + 4 * j];
}

// ---------------------------------------------------------------------------
// Level 0 v2 (best replay structure), x1 addressing parameterized so the same
// kernel reads either the dense-gathered x1s (fast) or raw x1 (no-ws fallback).
//   x1 element (b, c, row i_r, col-index lane): x1b[b*BS + i_r*RS + lane*CS + c*CCS]
// ---------------------------------------------------------------------------
__global__ __launch_bounds__(256) void corr0_kernel(
    const float* __restrict__ x1b, long BS, long RS, int CS, long CCS,
    const float* __restrict__ x2, float* __restrict__ out) {
  int bx = blockIdx.x;
  int L = (bx & 7) * 96 + (bx >> 3);          // 768 = 8 * 96 (bijective)
  int y = L % 192, b = L / 192;
  int tid = threadIdx.x;
  int w = tid >> 6, lane = tid & 63;
  int i_lo = (y - 1) / 4; if (i_lo < 0) i_lo = 0;   // valid i range for this y
  int i_hi = (y + 4) / 4; if (i_hi > 47) i_hi = 47;
  int NI = i_hi - i_lo + 1;                   // 1..3

  __shared__ float red[4][34][64];            // 27 acc + 4 sq + 3 s1 slots
  __shared__ float inv2s[264];                // pads [0..3],[260..263] = 0
  __shared__ float inv1s[3][64];

  float acc[3][9];
#pragma unroll
  for (int r = 0; r < 3; ++r)
#pragma unroll
    for (int v = 0; v < 9; ++v) acc[r][v] = 0.f;
  float sq0 = 0.f, sq1 = 0.f, sq2 = 0.f, sq3 = 0.f;
  float s1[3] = {0.f, 0.f, 0.f};

  const float* x2row = x2 + (long)b * 12582912 + (long)y * 256 + 4 * lane;
  const float* x1p[3];
#pragma unroll
  for (int r = 0; r < 3; ++r) {
    int ir = i_lo + r; if (ir > 47) ir = 47;  // clamp (discarded if r>=NI)
    x1p[r] = x1b + (long)b * BS + (long)ir * RS + (long)lane * CS;
  }

#pragma unroll 4
  for (int cc = 0; cc < 64; ++cc) {
    int c = w * 64 + cc;
    long off2 = (long)c * 49152;
    long off1 = (long)c * CCS;
    float4 f = *reinterpret_cast<const float4*>(x2row + off2);
    sq0 += f.x * f.x; sq1 += f.y * f.y; sq2 += f.z * f.z; sq3 += f.w * f.w;
#pragma unroll
    for (int r = 0; r < 3; ++r) {
      float xv = x1p[r][off1];
      float xr = __shfl_down(xv, 1);          // x1 of lane j+1
      float xl = __shfl_up(xv, 1);            // x1 of lane j-1
      s1[r] += xv * xv;
      acc[r][0] += xr * f.x; acc[r][1] += xr * f.y;
      acc[r][2] += xr * f.z; acc[r][3] += xr * f.w;
      acc[r][4] += xv * f.x; acc[r][5] += xv * f.y;
      acc[r][6] += xv * f.z; acc[r][7] += xv * f.w;
      acc[r][8] += xl * f.x;
    }
  }

  // realign + dump to LDS: acc[v<4](j) lives at lane j-1; acc[8](j) at j+1.
#pragma unroll
  for (int r = 0; r < 3; ++r) {
    red[w][r * 9 + 0][lane] = __shfl_up(acc[r][0], 1);
    red[w][r * 9 + 1][lane] = __shfl_up(acc[r][1], 1);
    red[w][r * 9 + 2][lane] = __shfl_up(acc[r][2], 1);
    red[w][r * 9 + 3][lane] = __shfl_up(acc[r][3], 1);
    red[w][r * 9 + 4][lane] = acc[r][4];
    red[w][r * 9 + 5][lane] = acc[r][5];
    red[w][r * 9 + 6][lane] = acc[r][6];
    red[w][r * 9 + 7][lane] = acc[r][7];
    red[w][r * 9 + 8][lane] = __shfl_down(acc[r][8], 1);
    red[w][31 + r][lane] = s1[r];
  }
  red[w][27][lane] = sq0; red[w][28][lane] = sq1;
  red[w][29][lane] = sq2; red[w][30][lane] = sq3;
  __syncthreads();
  {
    int comp = tid & 3, jj = tid >> 2;        // col = tid (0..255)
    float ss = red[0][27 + comp][jj] + red[1][27 + comp][jj] +
               red[2][27 + comp][jj] + red[3][27 + comp][jj];
    inv2s[4 + tid] = 1.f / (sqrtf(ss) + EPSN);
    if (tid < 4) { inv2s[tid] = 0.f; inv2s[260 + tid] = 0.f; }
    if (tid < 192) {
      int r = tid >> 6, j = tid & 63;
      float t = red[0][31 + r][j] + red[1][31 + r][j] +
                red[2][31 + r][j] + red[3][31 + r][j];
      inv1s[r][j] = 1.f / (sqrtf(t) + EPSN);
    }
  }
  __syncthreads();
  int lim = NI * 576;
  for (int idx = tid; idx < lim; idx += 256) {
    int r = idx / 576, rem = idx - r * 576;
    int v = rem >> 6, j = rem & 63;
    int i_r = i_lo + r;
    int u_r = y - 4 * i_r + 4;                // in [0,8]
    float s = red[0][r * 9 + v][j] + red[1][r * 9 + v][j] +
              red[2][r * 9 + v][j] + red[3][r * 9 + v][j];
    out[(long)b * 1741824 + (long)u_r * 27648 + (long)v * 3072 + i_r * 64 + j] =
        s * inv1s[r][j] * inv2s[4 * j + v];   // 4 + (4j+v-4)
  }
}

// ---------------------------------------------------------------------------
// Zero-fill level-0 outputs with OOB x2 row: (i=0,u=0..3) and (i=47,u=8).
// ---------------------------------------------------------------------------
__global__ __launch_bounds__(256) void zfill0_kernel(float* __restrict__ out) {
  int idx = blockIdx.x * 256 + threadIdx.x;
  int b = idx / 2880, rem = idx - b * 2880;
  int k = rem / 576, rem2 = rem - k * 576;
  int v = rem2 >> 6, j = rem2 & 63;
  int u = (k < 4) ? k : 8;
  int i = (k < 4) ? 0 : 47;
  out[(long)b * 1741824 + (long)u * 27648 + (long)v * 3072 + i * 64 + j] = 0.f;
}

// ---------------------------------------------------------------------------
// Normalize + f16 + transpose level-1 tensors into ws (single-pass, passing).
// ---------------------------------------------------------------------------
__global__ __launch_bounds__(256) void xpose1_kernel(
    const float* __restrict__ x1, const float* __restrict__ x2,
    __fp16* __restrict__ o1, __fp16* __restrict__ o2) {
  int bx = blockIdx.x;                        // 384 = 2 * 4 * 48
  int tz = bx & 1; int rem = bx >> 1;
  int i = rem % 48, b = rem / 48;
  const float* src = tz ? x2 : x1;
  __fp16* dst = (tz ? o2 : o1) + (long)(b * 48 + i) * 16384;  // 64*256
  __shared__ uint32_t lds[64 * 128];          // 64 rows x 512 B
  __shared__ float sred[4][64];
  int t = threadIdx.x;
  int j = t & 63, cg = t >> 6;                // wave = cg
  const float* sp = src + (long)b * 786432 + (long)i * 64 + j;
  float vv[64];                               // this thread's 64 channels
  float ss = 0.f;
#pragma unroll
  for (int c8 = 0; c8 < 64; ++c8) {
    float v = sp[(long)(cg * 64 + c8) * 3072];
    vv[c8] = v;
    ss += v * v;
  }
  sred[cg][j] = ss;
  __syncthreads();
  float invv = 1.f / (sqrtf(sred[0][j] + sred[1][j] + sred[2][j] + sred[3][j]) + EPSN);
#pragma unroll
  for (int cb = 0; cb < 8; ++cb) {
    uint32_t pk[4];
#pragma unroll
    for (int e2 = 0; e2 < 4; ++e2) {
      int cl = cb * 8 + e2 * 2;               // static local channel index
      __fp16 h0 = (__fp16)(vv[cl] * invv);
      __fp16 h1 = (__fp16)(vv[cl + 1] * invv);
      pk[e2] = (uint32_t)__builtin_bit_cast(uint16_t, h0) |
               ((uint32_t)__builtin_bit_cast(uint16_t, h1) << 16);
    }
    int byteoff = j * 512 + ((cg * 128 + cb * 16) ^ ((j & 7) << 4));
    *reinterpret_cast<uint4*>(reinterpret_cast<char*>(lds) + byteoff) =
        make_uint4(pk[0], pk[1], pk[2], pk[3]);
  }
  __syncthreads();
#pragma unroll
  for (int rep = 0; rep < 8; ++rep) {
    int idx = rep * 256 + t;
    int jj = idx >> 5, cb = idx & 31;
    int byteoff = jj * 512 + ((cb * 16) ^ ((jj & 7) << 4));
    uint4 val = *reinterpret_cast<const uint4*>(
        reinterpret_cast<const char*>(lds) + byteoff);
    *reinterpret_cast<uint4*>(reinterpret_cast<char*>(dst) + jj * 512 + cb * 16) = val;
  }
}

// ---------------------------------------------------------------------------
// Level 1 via MFMA, zfill merged (unchanged, passing).
// ---------------------------------------------------------------------------
__device__ const int OFFS39[39] = {
    0, 1, -1, 2, -2, 3, -3, 4, -4, 5, -5, 6, -6, 8, -8, 9, -9, 10, -10,
    12, -12, 15, -15, 16, -16, 18, -18, 20, -20, 27, -27, 32, -32, 36, -36,
    48, -48, 64, -64};

__global__ __launch_bounds__(64) void corr1m_kernel(
    const __fp16* __restrict__ w1, const __fp16* __restrict__ w2,
    float* __restrict__ out) {
  const int dils[6] = {1, 2, 3, 5, 9, 16};
  int bx = blockIdx.x;
  int L = (bx & 7) * 936 + (bx >> 3);         // 7488 = 8 * 936 (bijective)
  int oi = L % 39, i = (L / 39) % 48, b = L / 1872;
  int o = OFFS39[oi];
  int y = i + o;
  bool valid = (y >= 0 && y < 48);
  int l = threadIdx.x;
  __shared__ float c_lds[64][65];

  if (valid) {
    int lm = l & 15, lk = l >> 4;
    const __fp16* A = w1 + (long)(b * 48 + i) * 16384;   // [j1][c]
    const __fp16* B = w2 + (long)(b * 48 + y) * 16384;   // [j2][c]
    f32x4 acc[4][4];
#pragma unroll
    for (int tm = 0; tm < 4; ++tm)
#pragma unroll
      for (int tn = 0; tn < 4; ++tn) acc[tm][tn] = (f32x4)0.f;

    for (int ks = 0; ks < 8; ++ks) {
      f16x8 af[4], bf[4];
      int ko = ks * 32 + lk * 8;
#pragma unroll
      for (int tm = 0; tm < 4; ++tm)
        af[tm] = __builtin_bit_cast(f16x8, *reinterpret_cast<const uint4*>(
                     A + (tm * 16 + lm) * 256 + ko));
#pragma unroll
      for (int tn = 0; tn < 4; ++tn)
        bf[tn] = __builtin_bit_cast(f16x8, *reinterpret_cast<const uint4*>(
                     B + (tn * 16 + lm) * 256 + ko));
#pragma unroll
      for (int tm = 0; tm < 4; ++tm)
#pragma unroll
        for (int tn = 0; tn < 4; ++tn)
          acc[tm][tn] = __builtin_amdgcn_mfma_f32_16x16x32_f16(
              af[tm], bf[tn], acc[tm][tn], 0, 0, 0);
    }
#pragma unroll
    for (int tm = 0; tm < 4; ++tm)
#pragma unroll
      for (int tn = 0; tn < 4; ++tn)
#pragma unroll
        for (int r = 0; r < 4; ++r)
          c_lds[tm * 16 + lk * 4 + r][tn * 16 + lm] = acc[tm][tn][r];
    LDS_FENCE();
  }

#pragma unroll
  for (int dI = 0; dI < 6; ++dI) {
    int d = dils[dI];
    if (o % d) continue;
    int ud = o / d;
    if (ud < -4 || ud > 4) continue;
    long ob = (long)b * 1741824 + (long)(1 + dI) * 248832 +
              (long)(ud + 4) * 27648 + (long)i * 64 + l;
#pragma unroll
    for (int v = 0; v < 9; ++v) {
      float val = 0.f;
      if (valid) {
        int j2 = l + (v - 4) * d;
        val = (j2 >= 0 && j2 < 64) ? c_lds[l][j2] : 0.f;
      }
      out[ob + (long)v * 3072] = val;
    }
  }
}

// ---------------------------------------------------------------------------
// Fallback level-1 (round-6 passing kernel) for small ws_size.
// ---------------------------------------------------------------------------
__global__ __launch_bounds__(64) void corr1_kernel(
    const float* __restrict__ x1, const float* __restrict__ x2,
    const float* __restrict__ ws, float* __restrict__ out) {
  int bx = blockIdx.x;
  int L = (bx & 7) * 1296 + (bx >> 3);
  int u = L % 9, dI = (L / 9) % 6, i = (L / 54) % 48, b = L / 2592;
  const int dils[6] = {1, 2, 3, 5, 9, 16};
  int d = dils[dI];
  int y = i + (u - 4) * d;
  int lane = threadIdx.x;
  long ob = (long)b * 1741824 + (long)(1 + dI) * 248832 + (long)u * 27648 +
            (long)i * 64 + lane;
  if (y < 0 || y >= 48) {
#pragma unroll
    for (int v = 0; v < 9; ++v) out[ob + v * 3072] = 0.f;
    return;
  }
  __shared__ uint4 x2t[192];
  x2t[lane] = make_uint4(0, 0, 0, 0);
  x2t[lane + 64] = make_uint4(0, 0, 0, 0);
  x2t[lane + 128] = make_uint4(0, 0, 0, 0);
  float acc[9];
#pragma unroll
  for (int v = 0; v < 9; ++v) acc[v] = 0.f;
  const float* x2row = x2 + (long)b * 786432 + (long)y * 64 + lane;
  const float* x1row = x1 + (long)b * 786432 + (long)i * 64 + lane;
#pragma unroll 1
  for (int cc8 = 0; cc8 < 32; ++cc8) {
    float x1v[8]; uint32_t xb[8];
#pragma unroll
    for (int cc = 0; cc < 8; ++cc) {
      long c = cc8 * 8 + cc;
      xb[cc] = __float_as_uint(x2row[c * 3072]) + 0x8000u;
      x1v[cc] = x1row[c * 3072];
    }
    uint4 pk;
    pk.x = (xb[0] >> 16) | (xb[1] & 0xffff0000u);
    pk.y = (xb[2] >> 16) | (xb[3] & 0xffff0000u);
    pk.z = (xb[4] >> 16) | (xb[5] & 0xffff0000u);
    pk.w = (xb[6] >> 16) | (xb[7] & 0xffff0000u);
    x2t[64 + lane] = pk;
    LDS_FENCE();
#pragma unroll
    for (int v = 0; v < 9; ++v) {
      uint4 q = x2t[64 + lane + (v - 4) * d];
      float s;
      s  = x1v[0] * __uint_as_float(q.x << 16);
      s += x1v[1] * __uint_as_float(q.x & 0xffff0000u);
      s += x1v[2] * __uint_as_float(q.y << 16);
      s += x1v[3] * __uint_as_float(q.y & 0xffff0000u);
      s += x1v[4] * __uint_as_float(q.z << 16);
      s += x1v[5] * __uint_as_float(q.z & 0xffff0000u);
      s += x1v[6] * __uint_as_float(q.w << 16);
      s += x1v[7] * __uint_as_float(q.w & 0xffff0000u);
      acc[v] += s;
    }
    LDS_FENCE();
  }
  const float* i1 = ws + b * 3072 + i * 64;
  const float* i2 = ws + 12288 + b * 3072 + y * 64;
  float inv1 = i1[lane];
#pragma unroll
  for (int v = 0; v < 9; ++v) {
    int col = lane + (v - 4) * d;
    float i2v = (col >= 0 && col < 64) ? i2[col] : 0.f;
    out[ob + v * 3072] = acc[v] * inv1 * i2v;
  }
}

extern "C" void kernel_launch(void* const* d_in, const int* in_sizes, int n_in,
                              void* d_out, int out_size, void* d_ws, size_t ws_size,
                              hipStream_t stream) {
  const float* x1_0 = (const float*)d_in[0];
  const float* x1_1 = (const float*)d_in[1];
  const float* x2_0 = (const float*)d_in[2];
  const float* x2_1 = (const float*)d_in[3];
  float* out = (float*)d_out;
  float* ws = (float*)d_ws;
  if (ws_size >= 25264128) {
    float* x1s = (float*)((char*)d_ws + 12681216);
    gather1_kernel<<<12288, 256, 0, stream>>>(x1_0, x1s);
    corr0_kernel<<<768, 256, 0, stream>>>(x1s, 786432L, 64L, 1, 3072L,
                                          x2_0, out);
  } else {
    corr0_kernel<<<768, 256, 0, stream>>>(x1_0, 12582912L, 1024L, 4, 49152L,
                                          x2_0, out);
  }
  zfill0_kernel<<<45, 256, 0, stream>>>(out);
  if (ws_size >= 12681216) {
    __fp16* w1h = (__fp16*)((char*)d_ws + 98304);
    __fp16* w2h = w1h + 3145728;              // 4*48*64*256 elems
    xpose1_kernel<<<384, 256, 0, stream>>>(x1_1, x2_1, w1h, w2h);
    corr1m_kernel<<<7488, 64, 0, stream>>>(w1h, w2h, out);
  } else {
    norms1_kernel<<<96, 256, 0, stream>>>(x1_1, x2_1, ws);
    corr1_kernel<<<10368, 64, 0, stream>>>(x1_1, x2_1, ws, out);
  }
}